// Round 6
// baseline (693.952 us; speedup 1.0000x reference)
//
#include <hip/hip_runtime.h>

// Problem: B=4,S=2048,D=1024, C=16 chunks, N=2048 codewords, sub=64, K=1.
// pass1: split-bf16 MFMA screening with RUNTIME-CALIBRATED slot->(token,cw)
// decode (no layout assumptions). Certified argmin; ambiguous tokens exactly
// rescored by pass2. If ws_size < 1MB: proven R0 fp32 fallback (zero scratch).
constexpr int BS    = 8192;
constexpr int CCH   = 16;
constexpr int NCODE = 2048;

using s16x8 = __attribute__((ext_vector_type(8))) short;
using f32x4 = __attribute__((ext_vector_type(4))) float;

// ws (full path): float cbsq[32768] @0 | float cmax @131072 | int wcount @131076
//                 int wlist[131072] @131080  (total ~656 KB; requires ws>=1MB)

__device__ __forceinline__ unsigned short bf16_rne(float v) {
    unsigned u = __float_as_uint(v);
    return (unsigned short)((u + 0x7fffu + ((u >> 16) & 1u)) >> 16);
}
__device__ __forceinline__ void split1(float v, unsigned short& h, unsigned short& l) {
    h = bf16_rne(v);
    const float hf = __uint_as_float((unsigned)h << 16);
    l = bf16_rne(v - hf);                 // v-hf exact in fp32
}
__device__ __forceinline__ void split4(float4 v, ushort4& h, ushort4& l) {
    split1(v.x, h.x, l.x); split1(v.y, h.y, l.y);
    split1(v.z, h.z, l.z); split1(v.w, h.w, l.w);
}

// LDS tile: [row 0..127][k 0..63] bf16 (128 B/row); logical 16B chunk ch=k>>3
// stored at phys chunk (ch ^ row) & 7
__device__ __forceinline__ s16x8 ldfrag(const char* buf, int row, int ke) {
    return *(const s16x8*)(buf + row * 128 + ((((ke >> 3) ^ row) & 7) * 16));
}

__global__ void init_ws(float* cmax, int* wcount) {
    if (threadIdx.x == 0) { *cmax = 0.f; *wcount = 0; }
}

__global__ void cbsq_kernel(const float* __restrict__ cb, float* __restrict__ cbsq,
                            float* __restrict__ cmax)
{
    const int g = blockIdx.x * 256 + threadIdx.x;
    const float4* cg = (const float4*)cb;
    float s = 0.f;
#pragma unroll
    for (int q = 0; q < 16; ++q) {
        float4 v = cg[(size_t)g * 16 + q];
        s = fmaf(v.x, v.x, s); s = fmaf(v.y, v.y, s);
        s = fmaf(v.z, v.z, s); s = fmaf(v.w, v.w, s);
    }
    cbsq[g] = s;
    atomicMax((unsigned*)cmax, __float_as_uint(s));   // s >= 0
}

// =================== FALLBACK: proven R0 fp32 kernel (zero scratch) ===================
__global__ __launch_bounds__(256, 2)
void vq_fp32_fallback(const float* __restrict__ x, const float* __restrict__ cb,
                      float* __restrict__ out)
{
    __shared__ __align__(16) char smraw[65536];
    float4 (*xs)[128] = reinterpret_cast<float4(*)[128]>(smraw);
    float4 (*cs)[128] = reinterpret_cast<float4(*)[128]>(smraw + 32768);
    float  (*rs)[128] = reinterpret_cast<float(*)[128]>(smraw);
    int    (*ri)[128] = reinterpret_cast<int(*)[128]>(smraw + 8192);
    int    *bfin      = reinterpret_cast<int*>(smraw + 16384);

    const int tid = threadIdx.x, tx = tid & 15, ty = tid >> 4;
    const int c = blockIdx.y, mbase = blockIdx.x * 128;
    const float4* xg = (const float4*)x;
    const float4* cg = (const float4*)cb;
    {
        const int k4 = tid & 15, mrow0 = tid >> 4;
#pragma unroll
        for (int i = 0; i < 8; ++i) {
            const int m = i * 16 + mrow0;
            xs[k4][m] = xg[(size_t)(mbase + m) * 256 + c * 16 + k4];
        }
    }
    float best[8]; int bidx[8];
#pragma unroll
    for (int ii = 0; ii < 8; ++ii) { best[ii] = 3.4e38f; bidx[ii] = 0; }

    for (int nt = 0; nt < 16; ++nt) {
        __syncthreads();
        {
            const int k4 = tid & 15, nrow0 = tid >> 4;
#pragma unroll
            for (int i = 0; i < 8; ++i) {
                const int n = i * 16 + nrow0;
                cs[k4][n] = cg[((size_t)c * NCODE + nt * 128 + n) * 16 + k4];
            }
        }
        __syncthreads();
        float acc[8][8], csq[8];
#pragma unroll
        for (int ii = 0; ii < 8; ++ii)
#pragma unroll
            for (int jj = 0; jj < 8; ++jj) acc[ii][jj] = 0.f;
#pragma unroll
        for (int jj = 0; jj < 8; ++jj) csq[jj] = 0.f;
#pragma unroll 2
        for (int k4 = 0; k4 < 16; ++k4) {
            float4 xv[8], cv[8];
#pragma unroll
            for (int ii = 0; ii < 8; ++ii) xv[ii] = xs[k4][tx + 16 * ii];
#pragma unroll
            for (int jj = 0; jj < 8; ++jj) cv[jj] = cs[k4][ty + 16 * jj];
#pragma unroll
            for (int jj = 0; jj < 8; ++jj) {
                csq[jj] = fmaf(cv[jj].x, cv[jj].x, csq[jj]);
                csq[jj] = fmaf(cv[jj].y, cv[jj].y, csq[jj]);
                csq[jj] = fmaf(cv[jj].z, cv[jj].z, csq[jj]);
                csq[jj] = fmaf(cv[jj].w, cv[jj].w, csq[jj]);
            }
#pragma unroll
            for (int ii = 0; ii < 8; ++ii)
#pragma unroll
                for (int jj = 0; jj < 8; ++jj) {
                    acc[ii][jj] = fmaf(xv[ii].x, cv[jj].x, acc[ii][jj]);
                    acc[ii][jj] = fmaf(xv[ii].y, cv[jj].y, acc[ii][jj]);
                    acc[ii][jj] = fmaf(xv[ii].z, cv[jj].z, acc[ii][jj]);
                    acc[ii][jj] = fmaf(xv[ii].w, cv[jj].w, acc[ii][jj]);
                }
        }
#pragma unroll
        for (int jj = 0; jj < 8; ++jj) {
            const int n = nt * 128 + ty + 16 * jj;
#pragma unroll
            for (int ii = 0; ii < 8; ++ii) {
                const float s = fmaf(-2.f, acc[ii][jj], csq[jj]);
                if (s < best[ii]) { best[ii] = s; bidx[ii] = n; }
            }
        }
    }
    __syncthreads();
#pragma unroll
    for (int ii = 0; ii < 8; ++ii) {
        const int m = tx + 16 * ii;
        rs[ty][m] = best[ii]; ri[ty][m] = bidx[ii];
    }
    __syncthreads();
    if (tid < 128) {
        float b = rs[0][tid]; int bi = ri[0][tid];
#pragma unroll
        for (int j = 1; j < 16; ++j) {
            const float s = rs[j][tid]; const int i2 = ri[j][tid];
            if (s < b || (s == b && i2 < bi)) { b = s; bi = i2; }
        }
        bfin[tid] = bi;
    }
    __syncthreads();
    {
        float4* og = (float4*)out;
#pragma unroll
        for (int i = 0; i < 8; ++i) {
            const int flat = i * 256 + tid, m = flat >> 4, q = flat & 15;
            og[(size_t)(mbase + m) * 256 + c * 16 + q] =
                cg[((size_t)c * NCODE + bfin[m]) * 16 + q];
        }
    }
}

// =================== pass 1: calibrated split-bf16 MFMA ===================
__global__ __launch_bounds__(256, 2)
void pass1(const float* __restrict__ x, const float* __restrict__ cb,
           const float* __restrict__ cbsq, const float* __restrict__ cmax,
           float* __restrict__ out, int* __restrict__ wcount, int* __restrict__ wlist)
{
    __shared__ __align__(1024) char sm[65536];
    const int tid  = threadIdx.x;
    const int lane = tid & 63, wv = tid >> 6;
    const int l15  = lane & 15, quad = lane >> 4;
    const int c = blockIdx.y, mbase = blockIdx.x * 128;
    const float4* xg = (const float4*)x;
    const float4* cg = (const float4*)cb;
    const float cmaxs = sqrtf(*cmax);
    const int cwb = (wv & 1) * 64, tkb = (wv >> 1) * 64;

    // ---- calibration: decode slot -> (t_hat, n_hat) through the real pipeline.
    // calV[row][k] = row&15 (all k); calOnes[row][k] = 1.  Two k-constant GEMMs:
    //   acc_t = mfma(ones_frag, val_frag) -> 32 * t_hat   (immune to any k-perm)
    //   acc_n = mfma(val_frag, ones_frag) -> 32 * n_hat
    int tdec[4], ndec[4];
    {
        char* calV = sm;            // 16 KB
        char* calO = sm + 16384;    // 16 KB
#pragma unroll
        for (int i = 0; i < 8; ++i) {
            const int flat = i * 256 + tid, row = flat >> 4, f4c = flat & 15;
            const int off = row * 128 + ((((f4c >> 1) ^ row) & 7) * 16) + (f4c & 1) * 8;
            const unsigned short hv = bf16_rne((float)(row & 15));
            const unsigned short ho = bf16_rne(1.0f);
            ushort4 v4 = {hv, hv, hv, hv}, o4 = {ho, ho, ho, ho};
            *(ushort4*)(calV + off) = v4;
            *(ushort4*)(calO + off) = o4;
        }
        __syncthreads();
        const int ke = quad * 8;
        const s16x8 aV = ldfrag(calV, cwb + l15, ke);   // codeword-side values
        const s16x8 aO = ldfrag(calO, cwb + l15, ke);
        const s16x8 bV = ldfrag(calV, tkb + l15, ke);   // token-side values
        const s16x8 bO = ldfrag(calO, tkb + l15, ke);
        f32x4 z; z[0] = z[1] = z[2] = z[3] = 0.f;
        const f32x4 at = __builtin_amdgcn_mfma_f32_16x16x32_bf16(aO, bV, z, 0, 0, 0);
        const f32x4 an = __builtin_amdgcn_mfma_f32_16x16x32_bf16(aV, bO, z, 0, 0, 0);
#pragma unroll
        for (int r = 0; r < 4; ++r) {
            tdec[r] = ((int)(at[r] + 0.5f) >> 5) & 15;
            ndec[r] = ((int)(an[r] + 0.5f) >> 5) & 15;
        }
        __syncthreads();
    }

    // ---- stage x tile (split bf16 hi/lo, swizzled) into buf1 (0..32K)
    char* xs_hi = sm;
    char* xs_lo = sm + 16384;
    {
        float4 xf[8];
#pragma unroll
        for (int i = 0; i < 8; ++i) {
            const int flat = i * 256 + tid;
            xf[i] = xg[(size_t)(mbase + (flat >> 4)) * 256 + c * 16 + (flat & 15)];
        }
#pragma unroll
        for (int i = 0; i < 8; ++i) {
            const int flat = i * 256 + tid, row = flat >> 4, f4c = flat & 15;
            ushort4 h, l; split4(xf[i], h, l);
            const int off = row * 128 + ((((f4c >> 1) ^ row) & 7) * 16) + (f4c & 1) * 8;
            *(ushort4*)(xs_hi + off) = h;
            *(ushort4*)(xs_lo + off) = l;
        }
    }
    __syncthreads();

    // hoist token (B) fragments for the whole nt loop (xs dies at nt=1)
    s16x8 bhf[4][2], blf[4][2];
#pragma unroll
    for (int jt = 0; jt < 4; ++jt)
#pragma unroll
        for (int ks = 0; ks < 2; ++ks) {
            const int rowt = tkb + jt * 16 + l15;
            const int ke = ks * 32 + quad * 8;
            bhf[jt][ks] = ldfrag(xs_hi, rowt, ke);
            blf[jt][ks] = ldfrag(xs_lo, rowt, ke);
        }

    // prefetch codeword tile nt=0
    float4 pf[8];
    {
        const float4* src = cg + (size_t)c * NCODE * 16;
#pragma unroll
        for (int i = 0; i < 8; ++i) {
            const int flat = i * 256 + tid;
            pf[i] = src[(size_t)(flat >> 4) * 16 + (flat & 15)];
        }
    }

    // per-slot argmin state: slot (jt, r) -> token tkb+jt*16+tdec[r]
    float s1[4][4], s2[4][4]; int i1[4][4];
#pragma unroll
    for (int jt = 0; jt < 4; ++jt)
#pragma unroll
        for (int r = 0; r < 4; ++r) { s1[jt][r] = 3.4e38f; s2[jt][r] = 3.4e38f; i1[jt][r] = 0; }

    for (int nt = 0; nt < 16; ++nt) {
        char* chi = (nt & 1) ? sm : sm + 32768;
        char* clo = chi + 16384;
#pragma unroll
        for (int i = 0; i < 8; ++i) {
            const int flat = i * 256 + tid, row = flat >> 4, f4c = flat & 15;
            ushort4 h, l; split4(pf[i], h, l);
            const int off = row * 128 + ((((f4c >> 1) ^ row) & 7) * 16) + (f4c & 1) * 8;
            *(ushort4*)(chi + off) = h;
            *(ushort4*)(clo + off) = l;
        }
        __syncthreads();
        if (nt < 15) {
            const float4* src = cg + ((size_t)c * NCODE + (nt + 1) * 128) * 16;
#pragma unroll
            for (int i = 0; i < 8; ++i) {
                const int flat = i * 256 + tid;
                pf[i] = src[(size_t)(flat >> 4) * 16 + (flat & 15)];
            }
        }
        // codeword norms for this tile, addressed via decoded n_hat
        const float* cbn = cbsq + c * NCODE + nt * 128;
        float csqv[4][4];
#pragma unroll
        for (int mt = 0; mt < 4; ++mt)
#pragma unroll
            for (int r = 0; r < 4; ++r)
                csqv[mt][r] = cbn[cwb + mt * 16 + ndec[r]];

#pragma unroll
        for (int mt = 0; mt < 4; ++mt) {
            f32x4 accj[4];
#pragma unroll
            for (int jt = 0; jt < 4; ++jt)
#pragma unroll
                for (int e = 0; e < 4; ++e) accj[jt][e] = 0.f;
#pragma unroll
            for (int ks = 0; ks < 2; ++ks) {
                const int ke = ks * 32 + quad * 8;
                const int rowc = cwb + mt * 16 + l15;
                const s16x8 ah = ldfrag(chi, rowc, ke);
                const s16x8 al = ldfrag(clo, rowc, ke);
#pragma unroll
                for (int jt = 0; jt < 4; ++jt) {
                    accj[jt] = __builtin_amdgcn_mfma_f32_16x16x32_bf16(ah, bhf[jt][ks], accj[jt], 0, 0, 0);
                    accj[jt] = __builtin_amdgcn_mfma_f32_16x16x32_bf16(ah, blf[jt][ks], accj[jt], 0, 0, 0);
                    accj[jt] = __builtin_amdgcn_mfma_f32_16x16x32_bf16(al, bhf[jt][ks], accj[jt], 0, 0, 0);
                }
            }
            // epilogue: n = nt*128 + cwb + mt*16 + ndec[r]; ascending in (nt,mt)
            // per slot => strict < keeps numpy's first-index min.
#pragma unroll
            for (int jt = 0; jt < 4; ++jt)
#pragma unroll
                for (int r = 0; r < 4; ++r) {
                    const float s = fmaf(-2.f, accj[jt][r], csqv[mt][r]);
                    const int n = nt * 128 + cwb + mt * 16 + ndec[r];
                    const bool lt = s < s1[jt][r];
                    s2[jt][r] = fminf(s2[jt][r], fmaxf(s, s1[jt][r]));
                    i1[jt][r] = lt ? n : i1[jt][r];
                    s1[jt][r] = fminf(s1[jt][r], s);
                }
        }
    }

    __syncthreads();   // all waves done with tile buffers
    // merge via LDS keyed by DECODED (token, n_hat): bijective per wave
    float* s1a = (float*)sm;                // [128][32]
    int*   i1a = (int*)(sm + 16384);
    float* s2a = (float*)(sm + 32768);
    float* sm_part = (float*)(sm + 49152);  // [128][16]
    int*   bfin    = (int*)(sm + 57344);    // [128]
#pragma unroll
    for (int jt = 0; jt < 4; ++jt)
#pragma unroll
        for (int r = 0; r < 4; ++r) {
            const int tok = tkb + jt * 16 + tdec[r];
            const int idx = tok * 32 + (wv & 1) * 16 + ndec[r];
            s1a[idx] = s1[jt][r]; i1a[idx] = i1[jt][r]; s2a[idx] = s2[jt][r];
        }
    // xsq partials (global re-read; L2/L3-hot)
    {
        const float4* src = xg + (size_t)mbase * 256 + c * 16;
#pragma unroll
        for (int i = 0; i < 8; ++i) {
            const int flat = i * 256 + tid, row = flat >> 4, f4c = flat & 15;
            const float4 v = src[(size_t)row * 256 + f4c];
            sm_part[row * 16 + f4c] = v.x * v.x + v.y * v.y + v.z * v.z + v.w * v.w;
        }
    }
    __syncthreads();
    if (tid < 128) {
        float b1 = 3.4e38f, b2 = 3.4e38f; int bi = 0;
#pragma unroll 4
        for (int e = 0; e < 32; ++e) {
            const float se = s1a[tid * 32 + e];
            const int   ie = i1a[tid * 32 + e];
            const float s2e = s2a[tid * 32 + e];
            if (se < b1 || (se == b1 && ie < bi)) { b2 = fminf(b2, b1); b1 = se; bi = ie; }
            else b2 = fminf(b2, se);
            b2 = fminf(b2, s2e);
        }
        float xsq = 0.f;
#pragma unroll
        for (int q = 0; q < 16; ++q) xsq += sm_part[tid * 16 + q];
        // analytic score error <= ~2e-5*||x||*||c||; ~30x margin
        const float eps = 2e-3f + 6e-4f * sqrtf(xsq) * cmaxs;
        bfin[tid] = bi;
        if (b2 - b1 <= 2.f * eps) {
            const int slot = atomicAdd(wcount, 1);
            if (slot < 131072) wlist[slot] = (mbase + tid) * 16 + c;
        }
    }
    __syncthreads();
    {
        float4* og = (float4*)out;
#pragma unroll
        for (int i = 0; i < 8; ++i) {
            const int flat = i * 256 + tid, m = flat >> 4, q = flat & 15;
            og[(size_t)(mbase + m) * 256 + c * 16 + q] =
                cg[((size_t)c * NCODE + bfin[m]) * 16 + q];
        }
    }
}

// =================== pass 2: exact fp32 rescore ===================
__global__ __launch_bounds__(256, 4)
void pass2(const float* __restrict__ x, const float* __restrict__ cb,
           const float* __restrict__ cbsq, float* __restrict__ out,
           const int* __restrict__ wcount, const int* __restrict__ wlist)
{
    __shared__ float xls[64];
    __shared__ float rb[256];
    __shared__ int   rix[256];
    const float4* xg = (const float4*)x;
    const float4* cg = (const float4*)cb;
    float4* og = (float4*)out;
    const int tid = threadIdx.x;
    const int total = *wcount;
    const bool scan_all = (total > 131072);      // safety: rescore everything
    const int count = scan_all ? 131072 : total;

    for (int e = blockIdx.x; e < count; e += gridDim.x) {
        const int id = scan_all ? e : wlist[e];
        const int m = id >> 4, c = id & 15;
        __syncthreads();
        if (tid < 16) ((float4*)xls)[tid] = xg[(size_t)m * 256 + c * 16 + tid];
        __syncthreads();
        float best = 3.4e38f; int bi = 0;
        for (int i = 0; i < 8; ++i) {
            const int n = tid * 8 + i;
            const float4* crow = cg + ((size_t)c * NCODE + n) * 16;
            float dot = 0.f;
#pragma unroll
            for (int q = 0; q < 16; ++q) {
                const float4 v = crow[q];
                dot = fmaf(v.x, xls[4 * q + 0], dot);
                dot = fmaf(v.y, xls[4 * q + 1], dot);
                dot = fmaf(v.z, xls[4 * q + 2], dot);
                dot = fmaf(v.w, xls[4 * q + 3], dot);
            }
            const float s = fmaf(-2.f, dot, cbsq[c * NCODE + n]);
            if (s < best) { best = s; bi = n; }
        }
        rb[tid] = best; rix[tid] = bi;
        __syncthreads();
        for (int off = 128; off > 0; off >>= 1) {
            if (tid < off) {
                const float o = rb[tid + off];
                if (o < rb[tid]) { rb[tid] = o; rix[tid] = rix[tid + off]; }
            }
            __syncthreads();
        }
        if (tid < 16) {
            const int win = rix[0];
            og[(size_t)m * 256 + c * 16 + tid] = cg[((size_t)c * NCODE + win) * 16 + tid];
        }
    }
}

extern "C" void kernel_launch(void* const* d_in, const int* in_sizes, int n_in,
                              void* d_out, int out_size, void* d_ws, size_t ws_size,
                              hipStream_t stream)
{
    const float* x  = (const float*)d_in[0];
    const float* cb = (const float*)d_in[1];
    float* out      = (float*)d_out;

    if (ws_size < (size_t)(1u << 20)) {
        // scratch too small for wlist path: proven fp32 kernel, zero scratch
        dim3 grid(BS / 128, CCH);
        vq_fp32_fallback<<<grid, 256, 0, stream>>>(x, cb, out);
        return;
    }
    char* ws = (char*)d_ws;
    float* cbsq = (float*)ws;
    float* cmax = (float*)(ws + 131072);
    int*   wcnt = (int*)(ws + 131076);
    int*   wlist = (int*)(ws + 131080);

    init_ws<<<1, 64, 0, stream>>>(cmax, wcnt);
    cbsq_kernel<<<CCH * NCODE / 256, 256, 0, stream>>>(cb, cbsq, cmax);
    pass1<<<dim3(BS / 128, CCH), 256, 0, stream>>>(x, cb, cbsq, cmax, out, wcnt, wlist);
    pass2<<<512, 256, 0, stream>>>(x, cb, cbsq, out, wcnt, wlist);
}

// Round 7
// 513.562 us; speedup vs baseline: 1.3513x; 1.3513x over previous
//
#include <hip/hip_runtime.h>

// Problem: B=4,S=2048,D=1024, C=16 chunks, N=2048 codewords, sub=64, K=1.
// pass1: split-bf16 MFMA screening with RUNTIME-CALIBRATED slot->(token,cw)
// decode (the R6 fix -- keep forever). Certified argmin (eps ~1.7x analytic
// worst case); ambiguous tokens (~7%) exactly rescored by tile-based pass2
// with R0's proven fp32 arithmetic. Codebook presplit to bf16 hi/lo when
// ws permits (removes 64x-redundant split VALU from pass1's K-loop).
constexpr int BS    = 8192;
constexpr int CCH   = 16;
constexpr int NCODE = 2048;

using s16x8 = __attribute__((ext_vector_type(8))) short;
using f32x4 = __attribute__((ext_vector_type(4))) float;

// ws layout: float cbsq[32768] @0 | float cmax @131072 | int bcnt[16] @131076
//            int bwl[16][8192] @131328 (ends 655616; full path needs ws>=1MB,
//            proven by R6 counters) | cbh @1MB (4MB) | cbl @5MB (4MB)

__device__ __forceinline__ unsigned short bf16_rne(float v) {
    unsigned u = __float_as_uint(v);
    return (unsigned short)((u + 0x7fffu + ((u >> 16) & 1u)) >> 16);
}
__device__ __forceinline__ void split1(float v, unsigned short& h, unsigned short& l) {
    h = bf16_rne(v);
    const float hf = __uint_as_float((unsigned)h << 16);
    l = bf16_rne(v - hf);                 // v-hf exact in fp32
}
__device__ __forceinline__ void split4(float4 v, ushort4& h, ushort4& l) {
    split1(v.x, h.x, l.x); split1(v.y, h.y, l.y);
    split1(v.z, h.z, l.z); split1(v.w, h.w, l.w);
}

// LDS tile: [row 0..127][k 0..63] bf16 (128 B/row); logical 16B chunk ch=k>>3
// stored at phys chunk (ch ^ row) & 7
__device__ __forceinline__ s16x8 ldfrag(const char* buf, int row, int ke) {
    return *(const s16x8*)(buf + row * 128 + ((((ke >> 3) ^ row) & 7) * 16));
}

__global__ void init_ws(float* cmax, int* bcnt) {
    if (threadIdx.x == 0) *cmax = 0.f;
    if (threadIdx.x < 16) bcnt[threadIdx.x] = 0;
}

__global__ void cbsq_kernel(const float* __restrict__ cb, float* __restrict__ cbsq,
                            float* __restrict__ cmax)
{
    const int g = blockIdx.x * 256 + threadIdx.x;
    const float4* cg = (const float4*)cb;
    float s = 0.f;
#pragma unroll
    for (int q = 0; q < 16; ++q) {
        float4 v = cg[(size_t)g * 16 + q];
        s = fmaf(v.x, v.x, s); s = fmaf(v.y, v.y, s);
        s = fmaf(v.z, v.z, s); s = fmaf(v.w, v.w, s);
    }
    cbsq[g] = s;
    atomicMax((unsigned*)cmax, __float_as_uint(s));   // s >= 0
}

__global__ void presplit_cb(const float* __restrict__ cb,
                            unsigned short* __restrict__ cbh,
                            unsigned short* __restrict__ cbl)
{
    const int g = blockIdx.x * 256 + threadIdx.x;     // 0..524287 float4s
    const float4 v = ((const float4*)cb)[g];
    ushort4 h, l; split4(v, h, l);
    ((ushort4*)cbh)[g] = h;
    ((ushort4*)cbl)[g] = l;
}

// =================== FALLBACK: proven R0 fp32 kernel (zero scratch) ===================
__global__ __launch_bounds__(256, 2)
void vq_fp32_fallback(const float* __restrict__ x, const float* __restrict__ cb,
                      float* __restrict__ out)
{
    __shared__ __align__(16) char smraw[65536];
    float4 (*xs)[128] = reinterpret_cast<float4(*)[128]>(smraw);
    float4 (*cs)[128] = reinterpret_cast<float4(*)[128]>(smraw + 32768);
    float  (*rs)[128] = reinterpret_cast<float(*)[128]>(smraw);
    int    (*ri)[128] = reinterpret_cast<int(*)[128]>(smraw + 8192);
    int    *bfin      = reinterpret_cast<int*>(smraw + 16384);

    const int tid = threadIdx.x, tx = tid & 15, ty = tid >> 4;
    const int c = blockIdx.y, mbase = blockIdx.x * 128;
    const float4* xg = (const float4*)x;
    const float4* cg = (const float4*)cb;
    {
        const int k4 = tid & 15, mrow0 = tid >> 4;
#pragma unroll
        for (int i = 0; i < 8; ++i) {
            const int m = i * 16 + mrow0;
            xs[k4][m] = xg[(size_t)(mbase + m) * 256 + c * 16 + k4];
        }
    }
    float best[8]; int bidx[8];
#pragma unroll
    for (int ii = 0; ii < 8; ++ii) { best[ii] = 3.4e38f; bidx[ii] = 0; }
    for (int nt = 0; nt < 16; ++nt) {
        __syncthreads();
        {
            const int k4 = tid & 15, nrow0 = tid >> 4;
#pragma unroll
            for (int i = 0; i < 8; ++i) {
                const int n = i * 16 + nrow0;
                cs[k4][n] = cg[((size_t)c * NCODE + nt * 128 + n) * 16 + k4];
            }
        }
        __syncthreads();
        float acc[8][8], csq[8];
#pragma unroll
        for (int ii = 0; ii < 8; ++ii)
#pragma unroll
            for (int jj = 0; jj < 8; ++jj) acc[ii][jj] = 0.f;
#pragma unroll
        for (int jj = 0; jj < 8; ++jj) csq[jj] = 0.f;
#pragma unroll 2
        for (int k4 = 0; k4 < 16; ++k4) {
            float4 xv[8], cv[8];
#pragma unroll
            for (int ii = 0; ii < 8; ++ii) xv[ii] = xs[k4][tx + 16 * ii];
#pragma unroll
            for (int jj = 0; jj < 8; ++jj) cv[jj] = cs[k4][ty + 16 * jj];
#pragma unroll
            for (int jj = 0; jj < 8; ++jj) {
                csq[jj] = fmaf(cv[jj].x, cv[jj].x, csq[jj]);
                csq[jj] = fmaf(cv[jj].y, cv[jj].y, csq[jj]);
                csq[jj] = fmaf(cv[jj].z, cv[jj].z, csq[jj]);
                csq[jj] = fmaf(cv[jj].w, cv[jj].w, csq[jj]);
            }
#pragma unroll
            for (int ii = 0; ii < 8; ++ii)
#pragma unroll
                for (int jj = 0; jj < 8; ++jj) {
                    acc[ii][jj] = fmaf(xv[ii].x, cv[jj].x, acc[ii][jj]);
                    acc[ii][jj] = fmaf(xv[ii].y, cv[jj].y, acc[ii][jj]);
                    acc[ii][jj] = fmaf(xv[ii].z, cv[jj].z, acc[ii][jj]);
                    acc[ii][jj] = fmaf(xv[ii].w, cv[jj].w, acc[ii][jj]);
                }
        }
#pragma unroll
        for (int jj = 0; jj < 8; ++jj) {
            const int n = nt * 128 + ty + 16 * jj;
#pragma unroll
            for (int ii = 0; ii < 8; ++ii) {
                const float s = fmaf(-2.f, acc[ii][jj], csq[jj]);
                if (s < best[ii]) { best[ii] = s; bidx[ii] = n; }
            }
        }
    }
    __syncthreads();
#pragma unroll
    for (int ii = 0; ii < 8; ++ii) {
        const int m = tx + 16 * ii;
        rs[ty][m] = best[ii]; ri[ty][m] = bidx[ii];
    }
    __syncthreads();
    if (tid < 128) {
        float b = rs[0][tid]; int bi = ri[0][tid];
#pragma unroll
        for (int j = 1; j < 16; ++j) {
            const float s = rs[j][tid]; const int i2 = ri[j][tid];
            if (s < b || (s == b && i2 < bi)) { b = s; bi = i2; }
        }
        bfin[tid] = bi;
    }
    __syncthreads();
    {
        float4* og = (float4*)out;
#pragma unroll
        for (int i = 0; i < 8; ++i) {
            const int flat = i * 256 + tid, m = flat >> 4, q = flat & 15;
            og[(size_t)(mbase + m) * 256 + c * 16 + q] =
                cg[((size_t)c * NCODE + bfin[m]) * 16 + q];
        }
    }
}

// =================== pass 1: calibrated split-bf16 MFMA ===================
template<bool PRESPLIT>
__global__ __launch_bounds__(256, 2)
void pass1(const float* __restrict__ x, const float* __restrict__ cb,
           const unsigned short* __restrict__ cbh, const unsigned short* __restrict__ cbl,
           const float* __restrict__ cbsq, const float* __restrict__ cmax,
           float* __restrict__ out, int* __restrict__ bcnt, int* __restrict__ bwl)
{
    __shared__ __align__(1024) char sm[65536];
    const int tid  = threadIdx.x;
    const int lane = tid & 63, wv = tid >> 6;
    const int l15  = lane & 15, quad = lane >> 4;
    const int c = blockIdx.y, mbase = blockIdx.x * 128;
    const float4* xg = (const float4*)x;
    const float4* cg = (const float4*)cb;
    const float cmaxs = sqrtf(*cmax);
    const int cwb = (wv & 1) * 64, tkb = (wv >> 1) * 64;

    // ---- calibration (THE R6 fix): decode slot -> (t_hat, n_hat) through the
    // real stage->swizzle->ldfrag->MFMA pipeline. k-constant GEMMs:
    //   mfma(ones, val) -> 32 * t_hat ; mfma(val, ones) -> 32 * n_hat
    int tdec[4], ndec[4];
    {
        char* calV = sm;
        char* calO = sm + 16384;
#pragma unroll
        for (int i = 0; i < 8; ++i) {
            const int flat = i * 256 + tid, row = flat >> 4, f4c = flat & 15;
            const int off = row * 128 + ((((f4c >> 1) ^ row) & 7) * 16) + (f4c & 1) * 8;
            const unsigned short hv = bf16_rne((float)(row & 15));
            const unsigned short ho = bf16_rne(1.0f);
            ushort4 v4 = {hv, hv, hv, hv}, o4 = {ho, ho, ho, ho};
            *(ushort4*)(calV + off) = v4;
            *(ushort4*)(calO + off) = o4;
        }
        __syncthreads();
        const int ke = quad * 8;
        const s16x8 aV = ldfrag(calV, cwb + l15, ke);
        const s16x8 aO = ldfrag(calO, cwb + l15, ke);
        const s16x8 bV = ldfrag(calV, tkb + l15, ke);
        const s16x8 bO = ldfrag(calO, tkb + l15, ke);
        f32x4 z; z[0] = z[1] = z[2] = z[3] = 0.f;
        const f32x4 at = __builtin_amdgcn_mfma_f32_16x16x32_bf16(aO, bV, z, 0, 0, 0);
        const f32x4 an = __builtin_amdgcn_mfma_f32_16x16x32_bf16(aV, bO, z, 0, 0, 0);
#pragma unroll
        for (int r = 0; r < 4; ++r) {
            tdec[r] = ((int)(at[r] + 0.5f) >> 5) & 15;
            ndec[r] = ((int)(an[r] + 0.5f) >> 5) & 15;
        }
        __syncthreads();
    }

    // ---- stage x tile (split bf16 hi/lo, swizzled) into buf1 (0..32K)
    char* xs_hi = sm;
    char* xs_lo = sm + 16384;
    {
        float4 xf[8];
#pragma unroll
        for (int i = 0; i < 8; ++i) {
            const int flat = i * 256 + tid;
            xf[i] = xg[(size_t)(mbase + (flat >> 4)) * 256 + c * 16 + (flat & 15)];
        }
#pragma unroll
        for (int i = 0; i < 8; ++i) {
            const int flat = i * 256 + tid, row = flat >> 4, f4c = flat & 15;
            ushort4 h, l; split4(xf[i], h, l);
            const int off = row * 128 + ((((f4c >> 1) ^ row) & 7) * 16) + (f4c & 1) * 8;
            *(ushort4*)(xs_hi + off) = h;
            *(ushort4*)(xs_lo + off) = l;
        }
    }
    __syncthreads();

    // hoist token (B) fragments for the whole nt loop (xs dies at nt=1)
    s16x8 bhf[4][2], blf[4][2];
#pragma unroll
    for (int jt = 0; jt < 4; ++jt)
#pragma unroll
        for (int ks = 0; ks < 2; ++ks) {
            const int rowt = tkb + jt * 16 + l15;
            const int ke = ks * 32 + quad * 8;
            bhf[jt][ks] = ldfrag(xs_hi, rowt, ke);
            blf[jt][ks] = ldfrag(xs_lo, rowt, ke);
        }

    // prefetch codeword tile nt=0
    float4 pf[8];
    uint4  ph[4], pl[4];
    if (PRESPLIT) {
        const uint4* sh = (const uint4*)(cbh + (size_t)c * NCODE * 64);
        const uint4* sl = (const uint4*)(cbl + (size_t)c * NCODE * 64);
#pragma unroll
        for (int i = 0; i < 4; ++i) {
            const int flat = i * 256 + tid;
            ph[i] = sh[flat]; pl[i] = sl[flat];
        }
    } else {
        const float4* src = cg + (size_t)c * NCODE * 16;
#pragma unroll
        for (int i = 0; i < 8; ++i) {
            const int flat = i * 256 + tid;
            pf[i] = src[(size_t)(flat >> 4) * 16 + (flat & 15)];
        }
    }

    // per-slot argmin state: slot (jt, r) -> token tkb+jt*16+tdec[r]
    float s1[4][4], s2[4][4]; int i1[4][4];
#pragma unroll
    for (int jt = 0; jt < 4; ++jt)
#pragma unroll
        for (int r = 0; r < 4; ++r) { s1[jt][r] = 3.4e38f; s2[jt][r] = 3.4e38f; i1[jt][r] = 0; }

    for (int nt = 0; nt < 16; ++nt) {
        char* chi = (nt & 1) ? sm : sm + 32768;
        char* clo = chi + 16384;
        if (PRESPLIT) {
#pragma unroll
            for (int i = 0; i < 4; ++i) {
                const int flat = i * 256 + tid;          // uint4 index, 0..1023
                const int row = flat >> 3, ch = flat & 7;
                const int phys = (ch ^ row) & 7;
                *(uint4*)(chi + row * 128 + phys * 16) = ph[i];
                *(uint4*)(clo + row * 128 + phys * 16) = pl[i];
            }
        } else {
#pragma unroll
            for (int i = 0; i < 8; ++i) {
                const int flat = i * 256 + tid, row = flat >> 4, f4c = flat & 15;
                ushort4 h, l; split4(pf[i], h, l);
                const int off = row * 128 + ((((f4c >> 1) ^ row) & 7) * 16) + (f4c & 1) * 8;
                *(ushort4*)(chi + off) = h;
                *(ushort4*)(clo + off) = l;
            }
        }
        __syncthreads();
        if (nt < 15) {
            if (PRESPLIT) {
                const uint4* sh = (const uint4*)(cbh + ((size_t)c * NCODE + (nt + 1) * 128) * 64);
                const uint4* sl = (const uint4*)(cbl + ((size_t)c * NCODE + (nt + 1) * 128) * 64);
#pragma unroll
                for (int i = 0; i < 4; ++i) {
                    const int flat = i * 256 + tid;
                    ph[i] = sh[flat]; pl[i] = sl[flat];
                }
            } else {
                const float4* src = cg + ((size_t)c * NCODE + (nt + 1) * 128) * 16;
#pragma unroll
                for (int i = 0; i < 8; ++i) {
                    const int flat = i * 256 + tid;
                    pf[i] = src[(size_t)(flat >> 4) * 16 + (flat & 15)];
                }
            }
        }
        // codeword norms for this tile, addressed via decoded n_hat
        const float* cbn = cbsq + c * NCODE + nt * 128;
        float csqv[4][4];
#pragma unroll
        for (int mt = 0; mt < 4; ++mt)
#pragma unroll
            for (int r = 0; r < 4; ++r)
                csqv[mt][r] = cbn[cwb + mt * 16 + ndec[r]];

#pragma unroll
        for (int mt = 0; mt < 4; ++mt) {
            f32x4 accj[4];
#pragma unroll
            for (int jt = 0; jt < 4; ++jt)
#pragma unroll
                for (int e = 0; e < 4; ++e) accj[jt][e] = 0.f;
#pragma unroll
            for (int ks = 0; ks < 2; ++ks) {
                const int ke = ks * 32 + quad * 8;
                const int rowc = cwb + mt * 16 + l15;
                const s16x8 ah = ldfrag(chi, rowc, ke);
                const s16x8 al = ldfrag(clo, rowc, ke);
#pragma unroll
                for (int jt = 0; jt < 4; ++jt) {
                    accj[jt] = __builtin_amdgcn_mfma_f32_16x16x32_bf16(ah, bhf[jt][ks], accj[jt], 0, 0, 0);
                    accj[jt] = __builtin_amdgcn_mfma_f32_16x16x32_bf16(ah, blf[jt][ks], accj[jt], 0, 0, 0);
                    accj[jt] = __builtin_amdgcn_mfma_f32_16x16x32_bf16(al, bhf[jt][ks], accj[jt], 0, 0, 0);
                }
            }
            // n = nt*128 + cwb + mt*16 + ndec[r]: ascending in (nt,mt) per slot
            // => strict < keeps numpy's first-index min.
#pragma unroll
            for (int jt = 0; jt < 4; ++jt)
#pragma unroll
                for (int r = 0; r < 4; ++r) {
                    const float s = fmaf(-2.f, accj[jt][r], csqv[mt][r]);
                    const int n = nt * 128 + cwb + mt * 16 + ndec[r];
                    const bool lt = s < s1[jt][r];
                    s2[jt][r] = fminf(s2[jt][r], fmaxf(s, s1[jt][r]));
                    i1[jt][r] = lt ? n : i1[jt][r];
                    s1[jt][r] = fminf(s1[jt][r], s);
                }
        }
    }

    __syncthreads();   // all waves done with tile buffers
    // merge via LDS keyed by DECODED (token, n_hat): bijective per wave
    float* s1a = (float*)sm;                // [128][32]
    int*   i1a = (int*)(sm + 16384);
    float* s2a = (float*)(sm + 32768);
    float* sm_part = (float*)(sm + 49152);  // [128][16]
    int*   bfin    = (int*)(sm + 57344);    // [128]
#pragma unroll
    for (int jt = 0; jt < 4; ++jt)
#pragma unroll
        for (int r = 0; r < 4; ++r) {
            const int tok = tkb + jt * 16 + tdec[r];
            const int idx = tok * 32 + (wv & 1) * 16 + ndec[r];
            s1a[idx] = s1[jt][r]; i1a[idx] = i1[jt][r]; s2a[idx] = s2[jt][r];
        }
    // xsq partials (global re-read; L2/L3-hot)
    {
        const float4* src = xg + (size_t)mbase * 256 + c * 16;
#pragma unroll
        for (int i = 0; i < 8; ++i) {
            const int flat = i * 256 + tid, row = flat >> 4, f4c = flat & 15;
            const float4 v = src[(size_t)row * 256 + f4c];
            sm_part[row * 16 + f4c] = v.x * v.x + v.y * v.y + v.z * v.z + v.w * v.w;
        }
    }
    __syncthreads();
    if (tid < 128) {
        float b1 = 3.4e38f, b2 = 3.4e38f; int bi = 0;
#pragma unroll 4
        for (int e = 0; e < 32; ++e) {
            const float se = s1a[tid * 32 + e];
            const int   ie = i1a[tid * 32 + e];
            const float s2e = s2a[tid * 32 + e];
            if (se < b1 || (se == b1 && ie < bi)) { b2 = fminf(b2, b1); b1 = se; bi = ie; }
            else b2 = fminf(b2, se);
            b2 = fminf(b2, s2e);
        }
        float xsq = 0.f;
#pragma unroll
        for (int q = 0; q < 16; ++q) xsq += sm_part[tid * 16 + q];
        // worst-case |approx-fp32| <= ~1e-4*||x||*||c|| (dropped ll/r2 terms
        // 9.2e-5 + fp32-accum slack); coefficient 2e-4 ~= 1.7x margin.
        const float eps = 3e-4f + 2e-4f * sqrtf(xsq) * cmaxs;
        bfin[tid] = bi;
        if (b2 - b1 <= 2.f * eps) {
            const int slot = atomicAdd(&bcnt[c], 1);   // slot < 8192 structurally
            bwl[c * 8192 + slot] = mbase + tid;
        }
    }
    __syncthreads();
    {
        float4* og = (float4*)out;
#pragma unroll
        for (int i = 0; i < 8; ++i) {
            const int flat = i * 256 + tid, m = flat >> 4, q = flat & 15;
            og[(size_t)(mbase + m) * 256 + c * 16 + q] =
                cg[((size_t)c * NCODE + bfin[m]) * 16 + q];
        }
    }
}

// ====== pass 2: tile-based exact fp32 rescore (R0 arithmetic, bucketed) ======
__global__ __launch_bounds__(256, 2)
void pass2_tile(const float* __restrict__ x, const float* __restrict__ cb,
                float* __restrict__ out,
                const int* __restrict__ bcnt, const int* __restrict__ bwl)
{
    __shared__ __align__(16) char smraw[65536];
    __shared__ int toks[128];
    float4 (*xs)[128] = reinterpret_cast<float4(*)[128]>(smraw);
    float4 (*cs)[128] = reinterpret_cast<float4(*)[128]>(smraw + 32768);
    float  (*rs)[128] = reinterpret_cast<float(*)[128]>(smraw);
    int    (*ri)[128] = reinterpret_cast<int(*)[128]>(smraw + 8192);
    int    *bfin      = reinterpret_cast<int*>(smraw + 16384);

    const int c  = blockIdx.y;
    const int g0 = blockIdx.x * 128;
    const int cnt = bcnt[c];
    if (g0 >= cnt) return;
    const int tid = threadIdx.x, tx = tid & 15, ty = tid >> 4;
    const float4* xg = (const float4*)x;
    const float4* cg = (const float4*)cb;

    if (tid < 128) {
        const int e = g0 + tid;
        toks[tid] = bwl[c * 8192 + (e < cnt ? e : g0)];   // pad with dup of first
    }
    __syncthreads();
    {
        const int k4 = tid & 15, mrow0 = tid >> 4;
#pragma unroll
        for (int i = 0; i < 8; ++i) {
            const int m = i * 16 + mrow0;
            xs[k4][m] = xg[(size_t)toks[m] * 256 + c * 16 + k4];
        }
    }
    float best[8]; int bidx[8];
#pragma unroll
    for (int ii = 0; ii < 8; ++ii) { best[ii] = 3.4e38f; bidx[ii] = 0; }
    for (int nt = 0; nt < 16; ++nt) {
        __syncthreads();
        {
            const int k4 = tid & 15, nrow0 = tid >> 4;
#pragma unroll
            for (int i = 0; i < 8; ++i) {
                const int n = i * 16 + nrow0;
                cs[k4][n] = cg[((size_t)c * NCODE + nt * 128 + n) * 16 + k4];
            }
        }
        __syncthreads();
        float acc[8][8], csq[8];
#pragma unroll
        for (int ii = 0; ii < 8; ++ii)
#pragma unroll
            for (int jj = 0; jj < 8; ++jj) acc[ii][jj] = 0.f;
#pragma unroll
        for (int jj = 0; jj < 8; ++jj) csq[jj] = 0.f;
#pragma unroll 2
        for (int k4 = 0; k4 < 16; ++k4) {
            float4 xv[8], cv[8];
#pragma unroll
            for (int ii = 0; ii < 8; ++ii) xv[ii] = xs[k4][tx + 16 * ii];
#pragma unroll
            for (int jj = 0; jj < 8; ++jj) cv[jj] = cs[k4][ty + 16 * jj];
#pragma unroll
            for (int jj = 0; jj < 8; ++jj) {
                csq[jj] = fmaf(cv[jj].x, cv[jj].x, csq[jj]);
                csq[jj] = fmaf(cv[jj].y, cv[jj].y, csq[jj]);
                csq[jj] = fmaf(cv[jj].z, cv[jj].z, csq[jj]);
                csq[jj] = fmaf(cv[jj].w, cv[jj].w, csq[jj]);
            }
#pragma unroll
            for (int ii = 0; ii < 8; ++ii)
#pragma unroll
                for (int jj = 0; jj < 8; ++jj) {
                    acc[ii][jj] = fmaf(xv[ii].x, cv[jj].x, acc[ii][jj]);
                    acc[ii][jj] = fmaf(xv[ii].y, cv[jj].y, acc[ii][jj]);
                    acc[ii][jj] = fmaf(xv[ii].z, cv[jj].z, acc[ii][jj]);
                    acc[ii][jj] = fmaf(xv[ii].w, cv[jj].w, acc[ii][jj]);
                }
        }
#pragma unroll
        for (int jj = 0; jj < 8; ++jj) {
            const int n = nt * 128 + ty + 16 * jj;
#pragma unroll
            for (int ii = 0; ii < 8; ++ii) {
                const float s = fmaf(-2.f, acc[ii][jj], csq[jj]);
                if (s < best[ii]) { best[ii] = s; bidx[ii] = n; }
            }
        }
    }
    __syncthreads();
#pragma unroll
    for (int ii = 0; ii < 8; ++ii) {
        const int m = tx + 16 * ii;
        rs[ty][m] = best[ii]; ri[ty][m] = bidx[ii];
    }
    __syncthreads();
    if (tid < 128) {
        float b = rs[0][tid]; int bi = ri[0][tid];
#pragma unroll
        for (int j = 1; j < 16; ++j) {
            const float s = rs[j][tid]; const int i2 = ri[j][tid];
            if (s < b || (s == b && i2 < bi)) { b = s; bi = i2; }
        }
        bfin[tid] = bi;
    }
    __syncthreads();
    {
        float4* og = (float4*)out;
#pragma unroll
        for (int i = 0; i < 8; ++i) {
            const int flat = i * 256 + tid, m = flat >> 4, q = flat & 15;
            if (g0 + m < cnt) {
                og[(size_t)toks[m] * 256 + c * 16 + q] =
                    cg[((size_t)c * NCODE + bfin[m]) * 16 + q];
            }
        }
    }
}

extern "C" void kernel_launch(void* const* d_in, const int* in_sizes, int n_in,
                              void* d_out, int out_size, void* d_ws, size_t ws_size,
                              hipStream_t stream)
{
    const float* x  = (const float*)d_in[0];
    const float* cb = (const float*)d_in[1];
    float* out      = (float*)d_out;

    if (ws_size < (size_t)(1u << 20)) {
        dim3 grid(BS / 128, CCH);
        vq_fp32_fallback<<<grid, 256, 0, stream>>>(x, cb, out);
        return;
    }
    char* ws = (char*)d_ws;
    float* cbsq = (float*)ws;
    float* cmax = (float*)(ws + 131072);
    int*   bcnt = (int*)(ws + 131076);
    int*   bwl  = (int*)(ws + 131328);
    unsigned short* cbh = (unsigned short*)(ws + (1u << 20));
    unsigned short* cbl = (unsigned short*)(ws + (5u << 20));

    init_ws<<<1, 64, 0, stream>>>(cmax, bcnt);
    cbsq_kernel<<<CCH * NCODE / 256, 256, 0, stream>>>(cb, cbsq, cmax);
    if (ws_size >= (size_t)(9u << 20)) {
        presplit_cb<<<2048, 256, 0, stream>>>(cb, cbh, cbl);
        pass1<true><<<dim3(BS / 128, CCH), 256, 0, stream>>>(x, cb, cbh, cbl, cbsq, cmax, out, bcnt, bwl);
    } else {
        pass1<false><<<dim3(BS / 128, CCH), 256, 0, stream>>>(x, cb, nullptr, nullptr, cbsq, cmax, out, bcnt, bwl);
    }
    pass2_tile<<<dim3(64, CCH), 256, 0, stream>>>(x, cb, out, bcnt, bwl);
}

// Round 8
// 288.956 us; speedup vs baseline: 2.4016x; 1.7773x over previous
//
#include <hip/hip_runtime.h>

// Problem: B=4,S=2048,D=1024, C=16 chunks, N=2048 codewords, sub=64, K=1.
// pass1 (UNCHANGED from R7, proven absmax 0): calibrated split-bf16 MFMA
// screening + certified argmin. pass2: flagged tokens (~0.5%) exactly
// rescored with R0's fp32 arithmetic, parallelized over 16 codeword tiles
// x 16 chunks with packed-u64 atomicMin merge. pass3: gather winners.
constexpr int BS    = 8192;
constexpr int CCH   = 16;
constexpr int NCODE = 2048;

using s16x8 = __attribute__((ext_vector_type(8))) short;
using f32x4 = __attribute__((ext_vector_type(4))) float;

// ws layout: float cbsq[32768] @0 (128K) | float cmax @131072 | int bcnt[16] @131076
//   int bwl[16][8192] @131328 (512K) | u64 pbest[16][8192] @655616 (1M, 8-aligned)
//   -> full path needs 2 MB | bf16 cbh @2MB (4M), cbl @6MB (4M) -> presplit needs 10 MB

__device__ __forceinline__ unsigned short bf16_rne(float v) {
    unsigned u = __float_as_uint(v);
    return (unsigned short)((u + 0x7fffu + ((u >> 16) & 1u)) >> 16);
}
__device__ __forceinline__ void split1(float v, unsigned short& h, unsigned short& l) {
    h = bf16_rne(v);
    const float hf = __uint_as_float((unsigned)h << 16);
    l = bf16_rne(v - hf);                 // v-hf exact in fp32
}
__device__ __forceinline__ void split4(float4 v, ushort4& h, ushort4& l) {
    split1(v.x, h.x, l.x); split1(v.y, h.y, l.y);
    split1(v.z, h.z, l.z); split1(v.w, h.w, l.w);
}
// monotonic float->uint encoding (finite): a<b <=> enc(a)<enc(b)
__device__ __forceinline__ unsigned enc_f(float s) {
    unsigned u = __float_as_uint(s);
    return (u & 0x80000000u) ? ~u : (u | 0x80000000u);
}

// LDS tile: [row 0..127][k 0..63] bf16 (128 B/row); logical 16B chunk ch=k>>3
// stored at phys chunk (ch ^ row) & 7
__device__ __forceinline__ s16x8 ldfrag(const char* buf, int row, int ke) {
    return *(const s16x8*)(buf + row * 128 + ((((ke >> 3) ^ row) & 7) * 16));
}

__global__ void init_ws(float* cmax, int* bcnt) {
    if (threadIdx.x == 0) *cmax = 0.f;
    if (threadIdx.x < 16) bcnt[threadIdx.x] = 0;
}

__global__ void cbsq_kernel(const float* __restrict__ cb, float* __restrict__ cbsq,
                            float* __restrict__ cmax)
{
    const int g = blockIdx.x * 256 + threadIdx.x;
    const float4* cg = (const float4*)cb;
    float s = 0.f;
#pragma unroll
    for (int q = 0; q < 16; ++q) {
        float4 v = cg[(size_t)g * 16 + q];
        s = fmaf(v.x, v.x, s); s = fmaf(v.y, v.y, s);
        s = fmaf(v.z, v.z, s); s = fmaf(v.w, v.w, s);
    }
    cbsq[g] = s;
    atomicMax((unsigned*)cmax, __float_as_uint(s));   // s >= 0
}

__global__ void presplit_cb(const float* __restrict__ cb,
                            unsigned short* __restrict__ cbh,
                            unsigned short* __restrict__ cbl)
{
    const int g = blockIdx.x * 256 + threadIdx.x;     // 0..524287 float4s
    const float4 v = ((const float4*)cb)[g];
    ushort4 h, l; split4(v, h, l);
    ((ushort4*)cbh)[g] = h;
    ((ushort4*)cbl)[g] = l;
}

// =================== FALLBACK: proven R0 fp32 kernel (zero scratch) ===================
__global__ __launch_bounds__(256, 2)
void vq_fp32_fallback(const float* __restrict__ x, const float* __restrict__ cb,
                      float* __restrict__ out)
{
    __shared__ __align__(16) char smraw[65536];
    float4 (*xs)[128] = reinterpret_cast<float4(*)[128]>(smraw);
    float4 (*cs)[128] = reinterpret_cast<float4(*)[128]>(smraw + 32768);
    float  (*rs)[128] = reinterpret_cast<float(*)[128]>(smraw);
    int    (*ri)[128] = reinterpret_cast<int(*)[128]>(smraw + 8192);
    int    *bfin      = reinterpret_cast<int*>(smraw + 16384);

    const int tid = threadIdx.x, tx = tid & 15, ty = tid >> 4;
    const int c = blockIdx.y, mbase = blockIdx.x * 128;
    const float4* xg = (const float4*)x;
    const float4* cg = (const float4*)cb;
    {
        const int k4 = tid & 15, mrow0 = tid >> 4;
#pragma unroll
        for (int i = 0; i < 8; ++i) {
            const int m = i * 16 + mrow0;
            xs[k4][m] = xg[(size_t)(mbase + m) * 256 + c * 16 + k4];
        }
    }
    float best[8]; int bidx[8];
#pragma unroll
    for (int ii = 0; ii < 8; ++ii) { best[ii] = 3.4e38f; bidx[ii] = 0; }
    for (int nt = 0; nt < 16; ++nt) {
        __syncthreads();
        {
            const int k4 = tid & 15, nrow0 = tid >> 4;
#pragma unroll
            for (int i = 0; i < 8; ++i) {
                const int n = i * 16 + nrow0;
                cs[k4][n] = cg[((size_t)c * NCODE + nt * 128 + n) * 16 + k4];
            }
        }
        __syncthreads();
        float acc[8][8], csq[8];
#pragma unroll
        for (int ii = 0; ii < 8; ++ii)
#pragma unroll
            for (int jj = 0; jj < 8; ++jj) acc[ii][jj] = 0.f;
#pragma unroll
        for (int jj = 0; jj < 8; ++jj) csq[jj] = 0.f;
#pragma unroll 2
        for (int k4 = 0; k4 < 16; ++k4) {
            float4 xv[8], cv[8];
#pragma unroll
            for (int ii = 0; ii < 8; ++ii) xv[ii] = xs[k4][tx + 16 * ii];
#pragma unroll
            for (int jj = 0; jj < 8; ++jj) cv[jj] = cs[k4][ty + 16 * jj];
#pragma unroll
            for (int jj = 0; jj < 8; ++jj) {
                csq[jj] = fmaf(cv[jj].x, cv[jj].x, csq[jj]);
                csq[jj] = fmaf(cv[jj].y, cv[jj].y, csq[jj]);
                csq[jj] = fmaf(cv[jj].z, cv[jj].z, csq[jj]);
                csq[jj] = fmaf(cv[jj].w, cv[jj].w, csq[jj]);
            }
#pragma unroll
            for (int ii = 0; ii < 8; ++ii)
#pragma unroll
                for (int jj = 0; jj < 8; ++jj) {
                    acc[ii][jj] = fmaf(xv[ii].x, cv[jj].x, acc[ii][jj]);
                    acc[ii][jj] = fmaf(xv[ii].y, cv[jj].y, acc[ii][jj]);
                    acc[ii][jj] = fmaf(xv[ii].z, cv[jj].z, acc[ii][jj]);
                    acc[ii][jj] = fmaf(xv[ii].w, cv[jj].w, acc[ii][jj]);
                }
        }
#pragma unroll
        for (int jj = 0; jj < 8; ++jj) {
            const int n = nt * 128 + ty + 16 * jj;
#pragma unroll
            for (int ii = 0; ii < 8; ++ii) {
                const float s = fmaf(-2.f, acc[ii][jj], csq[jj]);
                if (s < best[ii]) { best[ii] = s; bidx[ii] = n; }
            }
        }
    }
    __syncthreads();
#pragma unroll
    for (int ii = 0; ii < 8; ++ii) {
        const int m = tx + 16 * ii;
        rs[ty][m] = best[ii]; ri[ty][m] = bidx[ii];
    }
    __syncthreads();
    if (tid < 128) {
        float b = rs[0][tid]; int bi = ri[0][tid];
#pragma unroll
        for (int j = 1; j < 16; ++j) {
            const float s = rs[j][tid]; const int i2 = ri[j][tid];
            if (s < b || (s == b && i2 < bi)) { b = s; bi = i2; }
        }
        bfin[tid] = bi;
    }
    __syncthreads();
    {
        float4* og = (float4*)out;
#pragma unroll
        for (int i = 0; i < 8; ++i) {
            const int flat = i * 256 + tid, m = flat >> 4, q = flat & 15;
            og[(size_t)(mbase + m) * 256 + c * 16 + q] =
                cg[((size_t)c * NCODE + bfin[m]) * 16 + q];
        }
    }
}

// =================== pass 1: calibrated split-bf16 MFMA (R7-proven) ===================
template<bool PRESPLIT>
__global__ __launch_bounds__(256, 2)
void pass1(const float* __restrict__ x, const float* __restrict__ cb,
           const unsigned short* __restrict__ cbh, const unsigned short* __restrict__ cbl,
           const float* __restrict__ cbsq, const float* __restrict__ cmax,
           float* __restrict__ out, int* __restrict__ bcnt, int* __restrict__ bwl,
           unsigned long long* __restrict__ pbest)
{
    __shared__ __align__(1024) char sm[65536];
    const int tid  = threadIdx.x;
    const int lane = tid & 63, wv = tid >> 6;
    const int l15  = lane & 15, quad = lane >> 4;
    const int c = blockIdx.y, mbase = blockIdx.x * 128;
    const float4* xg = (const float4*)x;
    const float4* cg = (const float4*)cb;
    const float cmaxs = sqrtf(*cmax);
    const int cwb = (wv & 1) * 64, tkb = (wv >> 1) * 64;

    // ---- calibration (THE R6 fix): decode slot -> (t_hat, n_hat) through the
    // real stage->swizzle->ldfrag->MFMA pipeline.
    int tdec[4], ndec[4];
    {
        char* calV = sm;
        char* calO = sm + 16384;
#pragma unroll
        for (int i = 0; i < 8; ++i) {
            const int flat = i * 256 + tid, row = flat >> 4, f4c = flat & 15;
            const int off = row * 128 + ((((f4c >> 1) ^ row) & 7) * 16) + (f4c & 1) * 8;
            const unsigned short hv = bf16_rne((float)(row & 15));
            const unsigned short ho = bf16_rne(1.0f);
            ushort4 v4 = {hv, hv, hv, hv}, o4 = {ho, ho, ho, ho};
            *(ushort4*)(calV + off) = v4;
            *(ushort4*)(calO + off) = o4;
        }
        __syncthreads();
        const int ke = quad * 8;
        const s16x8 aV = ldfrag(calV, cwb + l15, ke);
        const s16x8 aO = ldfrag(calO, cwb + l15, ke);
        const s16x8 bV = ldfrag(calV, tkb + l15, ke);
        const s16x8 bO = ldfrag(calO, tkb + l15, ke);
        f32x4 z; z[0] = z[1] = z[2] = z[3] = 0.f;
        const f32x4 at = __builtin_amdgcn_mfma_f32_16x16x32_bf16(aO, bV, z, 0, 0, 0);
        const f32x4 an = __builtin_amdgcn_mfma_f32_16x16x32_bf16(aV, bO, z, 0, 0, 0);
#pragma unroll
        for (int r = 0; r < 4; ++r) {
            tdec[r] = ((int)(at[r] + 0.5f) >> 5) & 15;
            ndec[r] = ((int)(an[r] + 0.5f) >> 5) & 15;
        }
        __syncthreads();
    }

    // ---- stage x tile (split bf16 hi/lo, swizzled) into buf1 (0..32K)
    char* xs_hi = sm;
    char* xs_lo = sm + 16384;
    {
        float4 xf[8];
#pragma unroll
        for (int i = 0; i < 8; ++i) {
            const int flat = i * 256 + tid;
            xf[i] = xg[(size_t)(mbase + (flat >> 4)) * 256 + c * 16 + (flat & 15)];
        }
#pragma unroll
        for (int i = 0; i < 8; ++i) {
            const int flat = i * 256 + tid, row = flat >> 4, f4c = flat & 15;
            ushort4 h, l; split4(xf[i], h, l);
            const int off = row * 128 + ((((f4c >> 1) ^ row) & 7) * 16) + (f4c & 1) * 8;
            *(ushort4*)(xs_hi + off) = h;
            *(ushort4*)(xs_lo + off) = l;
        }
    }
    __syncthreads();

    // hoist token (B) fragments for the whole nt loop (xs dies at nt=1)
    s16x8 bhf[4][2], blf[4][2];
#pragma unroll
    for (int jt = 0; jt < 4; ++jt)
#pragma unroll
        for (int ks = 0; ks < 2; ++ks) {
            const int rowt = tkb + jt * 16 + l15;
            const int ke = ks * 32 + quad * 8;
            bhf[jt][ks] = ldfrag(xs_hi, rowt, ke);
            blf[jt][ks] = ldfrag(xs_lo, rowt, ke);
        }

    // prefetch codeword tile nt=0
    float4 pf[8];
    uint4  ph[4], pl[4];
    if (PRESPLIT) {
        const uint4* sh = (const uint4*)(cbh + (size_t)c * NCODE * 64);
        const uint4* sl = (const uint4*)(cbl + (size_t)c * NCODE * 64);
#pragma unroll
        for (int i = 0; i < 4; ++i) {
            const int flat = i * 256 + tid;
            ph[i] = sh[flat]; pl[i] = sl[flat];
        }
    } else {
        const float4* src = cg + (size_t)c * NCODE * 16;
#pragma unroll
        for (int i = 0; i < 8; ++i) {
            const int flat = i * 256 + tid;
            pf[i] = src[(size_t)(flat >> 4) * 16 + (flat & 15)];
        }
    }

    float s1[4][4], s2[4][4]; int i1[4][4];
#pragma unroll
    for (int jt = 0; jt < 4; ++jt)
#pragma unroll
        for (int r = 0; r < 4; ++r) { s1[jt][r] = 3.4e38f; s2[jt][r] = 3.4e38f; i1[jt][r] = 0; }

    for (int nt = 0; nt < 16; ++nt) {
        char* chi = (nt & 1) ? sm : sm + 32768;
        char* clo = chi + 16384;
        if (PRESPLIT) {
#pragma unroll
            for (int i = 0; i < 4; ++i) {
                const int flat = i * 256 + tid;          // uint4 index, 0..1023
                const int row = flat >> 3, ch = flat & 7;
                const int phys = (ch ^ row) & 7;
                *(uint4*)(chi + row * 128 + phys * 16) = ph[i];
                *(uint4*)(clo + row * 128 + phys * 16) = pl[i];
            }
        } else {
#pragma unroll
            for (int i = 0; i < 8; ++i) {
                const int flat = i * 256 + tid, row = flat >> 4, f4c = flat & 15;
                ushort4 h, l; split4(pf[i], h, l);
                const int off = row * 128 + ((((f4c >> 1) ^ row) & 7) * 16) + (f4c & 1) * 8;
                *(ushort4*)(chi + off) = h;
                *(ushort4*)(clo + off) = l;
            }
        }
        __syncthreads();
        if (nt < 15) {
            if (PRESPLIT) {
                const uint4* sh = (const uint4*)(cbh + ((size_t)c * NCODE + (nt + 1) * 128) * 64);
                const uint4* sl = (const uint4*)(cbl + ((size_t)c * NCODE + (nt + 1) * 128) * 64);
#pragma unroll
                for (int i = 0; i < 4; ++i) {
                    const int flat = i * 256 + tid;
                    ph[i] = sh[flat]; pl[i] = sl[flat];
                }
            } else {
                const float4* src = cg + ((size_t)c * NCODE + (nt + 1) * 128) * 16;
#pragma unroll
                for (int i = 0; i < 8; ++i) {
                    const int flat = i * 256 + tid;
                    pf[i] = src[(size_t)(flat >> 4) * 16 + (flat & 15)];
                }
            }
        }
        const float* cbn = cbsq + c * NCODE + nt * 128;
        float csqv[4][4];
#pragma unroll
        for (int mt = 0; mt < 4; ++mt)
#pragma unroll
            for (int r = 0; r < 4; ++r)
                csqv[mt][r] = cbn[cwb + mt * 16 + ndec[r]];

#pragma unroll
        for (int mt = 0; mt < 4; ++mt) {
            f32x4 accj[4];
#pragma unroll
            for (int jt = 0; jt < 4; ++jt)
#pragma unroll
                for (int e = 0; e < 4; ++e) accj[jt][e] = 0.f;
#pragma unroll
            for (int ks = 0; ks < 2; ++ks) {
                const int ke = ks * 32 + quad * 8;
                const int rowc = cwb + mt * 16 + l15;
                const s16x8 ah = ldfrag(chi, rowc, ke);
                const s16x8 al = ldfrag(clo, rowc, ke);
#pragma unroll
                for (int jt = 0; jt < 4; ++jt) {
                    accj[jt] = __builtin_amdgcn_mfma_f32_16x16x32_bf16(ah, bhf[jt][ks], accj[jt], 0, 0, 0);
                    accj[jt] = __builtin_amdgcn_mfma_f32_16x16x32_bf16(ah, blf[jt][ks], accj[jt], 0, 0, 0);
                    accj[jt] = __builtin_amdgcn_mfma_f32_16x16x32_bf16(al, bhf[jt][ks], accj[jt], 0, 0, 0);
                }
            }
            // n ascending in (nt,mt) per slot => strict < keeps first-index min
#pragma unroll
            for (int jt = 0; jt < 4; ++jt)
#pragma unroll
                for (int r = 0; r < 4; ++r) {
                    const float s = fmaf(-2.f, accj[jt][r], csqv[mt][r]);
                    const int n = nt * 128 + cwb + mt * 16 + ndec[r];
                    const bool lt = s < s1[jt][r];
                    s2[jt][r] = fminf(s2[jt][r], fmaxf(s, s1[jt][r]));
                    i1[jt][r] = lt ? n : i1[jt][r];
                    s1[jt][r] = fminf(s1[jt][r], s);
                }
        }
    }

    __syncthreads();
    float* s1a = (float*)sm;                // [128][32]
    int*   i1a = (int*)(sm + 16384);
    float* s2a = (float*)(sm + 32768);
    float* sm_part = (float*)(sm + 49152);  // [128][16]
    int*   bfin    = (int*)(sm + 57344);    // [128]
#pragma unroll
    for (int jt = 0; jt < 4; ++jt)
#pragma unroll
        for (int r = 0; r < 4; ++r) {
            const int tok = tkb + jt * 16 + tdec[r];
            const int idx = tok * 32 + (wv & 1) * 16 + ndec[r];
            s1a[idx] = s1[jt][r]; i1a[idx] = i1[jt][r]; s2a[idx] = s2[jt][r];
        }
    {
        const float4* src = xg + (size_t)mbase * 256 + c * 16;
#pragma unroll
        for (int i = 0; i < 8; ++i) {
            const int flat = i * 256 + tid, row = flat >> 4, f4c = flat & 15;
            const float4 v = src[(size_t)row * 256 + f4c];
            sm_part[row * 16 + f4c] = v.x * v.x + v.y * v.y + v.z * v.z + v.w * v.w;
        }
    }
    __syncthreads();
    if (tid < 128) {
        float b1 = 3.4e38f, b2 = 3.4e38f; int bi = 0;
#pragma unroll 4
        for (int e = 0; e < 32; ++e) {
            const float se = s1a[tid * 32 + e];
            const int   ie = i1a[tid * 32 + e];
            const float s2e = s2a[tid * 32 + e];
            if (se < b1 || (se == b1 && ie < bi)) { b2 = fminf(b2, b1); b1 = se; bi = ie; }
            else b2 = fminf(b2, se);
            b2 = fminf(b2, s2e);
        }
        float xsq = 0.f;
#pragma unroll
        for (int q = 0; q < 16; ++q) xsq += sm_part[tid * 16 + q];
        const float eps = 3e-4f + 2e-4f * sqrtf(xsq) * cmaxs;
        bfin[tid] = bi;
        if (b2 - b1 <= 2.f * eps) {
            const int slot = atomicAdd(&bcnt[c], 1);   // slot < 8192 structurally
            bwl[c * 8192 + slot] = mbase + tid;
            pbest[c * 8192 + slot] = ~0ULL;            // init merge cell
        }
    }
    __syncthreads();
    {
        float4* og = (float4*)out;
#pragma unroll
        for (int i = 0; i < 8; ++i) {
            const int flat = i * 256 + tid, m = flat >> 4, q = flat & 15;
            og[(size_t)(mbase + m) * 256 + c * 16 + q] =
                cg[((size_t)c * NCODE + bfin[m]) * 16 + q];
        }
    }
}

// ====== pass 2: exact fp32 rescore, PARALLEL over 16 codeword tiles ======
__global__ __launch_bounds__(256, 2)
void pass2_nt(const float* __restrict__ x, const float* __restrict__ cb,
              const int* __restrict__ bcnt, const int* __restrict__ bwl,
              unsigned long long* __restrict__ pbest)
{
    __shared__ __align__(16) char smraw[65536];
    __shared__ int toks[128];
    float4 (*xs)[128] = reinterpret_cast<float4(*)[128]>(smraw);
    float4 (*cs)[128] = reinterpret_cast<float4(*)[128]>(smraw + 32768);
    float  (*rs)[128] = reinterpret_cast<float(*)[128]>(smraw);
    int    (*ri)[128] = reinterpret_cast<int(*)[128]>(smraw + 8192);

    const int c = blockIdx.y, ntb = blockIdx.x;
    const int cnt = bcnt[c];
    if (cnt == 0) return;
    const int tid = threadIdx.x, tx = tid & 15, ty = tid >> 4;
    const float4* xg = (const float4*)x;
    const float4* cg = (const float4*)cb;

    // stage this block's 128-codeword tile once (region disjoint from xs/rs)
    {
        const int k4 = tid & 15, nrow0 = tid >> 4;
#pragma unroll
        for (int i = 0; i < 8; ++i) {
            const int n = i * 16 + nrow0;
            cs[k4][n] = cg[((size_t)c * NCODE + ntb * 128 + n) * 16 + k4];
        }
    }

    for (int g0 = 0; g0 < cnt; g0 += 128) {
        __syncthreads();    // prior rs/xs reads done; cs staged (1st iter)
        if (tid < 128) {
            const int e = g0 + tid;
            toks[tid] = bwl[c * 8192 + (e < cnt ? e : g0)];   // pad: dup first
        }
        __syncthreads();
        {
            const int k4 = tid & 15, mrow0 = tid >> 4;
#pragma unroll
            for (int i = 0; i < 8; ++i) {
                const int m = i * 16 + mrow0;
                xs[k4][m] = xg[(size_t)toks[m] * 256 + c * 16 + k4];
            }
        }
        __syncthreads();
        float acc[8][8], csq[8];
#pragma unroll
        for (int ii = 0; ii < 8; ++ii)
#pragma unroll
            for (int jj = 0; jj < 8; ++jj) acc[ii][jj] = 0.f;
#pragma unroll
        for (int jj = 0; jj < 8; ++jj) csq[jj] = 0.f;
#pragma unroll 2
        for (int k4 = 0; k4 < 16; ++k4) {
            float4 xv[8], cv[8];
#pragma unroll
            for (int ii = 0; ii < 8; ++ii) xv[ii] = xs[k4][tx + 16 * ii];
#pragma unroll
            for (int jj = 0; jj < 8; ++jj) cv[jj] = cs[k4][ty + 16 * jj];
#pragma unroll
            for (int jj = 0; jj < 8; ++jj) {
                csq[jj] = fmaf(cv[jj].x, cv[jj].x, csq[jj]);
                csq[jj] = fmaf(cv[jj].y, cv[jj].y, csq[jj]);
                csq[jj] = fmaf(cv[jj].z, cv[jj].z, csq[jj]);
                csq[jj] = fmaf(cv[jj].w, cv[jj].w, csq[jj]);
            }
#pragma unroll
            for (int ii = 0; ii < 8; ++ii)
#pragma unroll
                for (int jj = 0; jj < 8; ++jj) {
                    acc[ii][jj] = fmaf(xv[ii].x, cv[jj].x, acc[ii][jj]);
                    acc[ii][jj] = fmaf(xv[ii].y, cv[jj].y, acc[ii][jj]);
                    acc[ii][jj] = fmaf(xv[ii].z, cv[jj].z, acc[ii][jj]);
                    acc[ii][jj] = fmaf(xv[ii].w, cv[jj].w, acc[ii][jj]);
                }
        }
        float best[8]; int bidx[8];
#pragma unroll
        for (int ii = 0; ii < 8; ++ii) { best[ii] = 3.4e38f; bidx[ii] = 0; }
#pragma unroll
        for (int jj = 0; jj < 8; ++jj) {
            const int n = ntb * 128 + ty + 16 * jj;
#pragma unroll
            for (int ii = 0; ii < 8; ++ii) {
                const float s = fmaf(-2.f, acc[ii][jj], csq[jj]);
                if (s < best[ii]) { best[ii] = s; bidx[ii] = n; }
            }
        }
        __syncthreads();    // xs reads done before rs alias writes
#pragma unroll
        for (int ii = 0; ii < 8; ++ii) {
            const int m = tx + 16 * ii;
            rs[ty][m] = best[ii]; ri[ty][m] = bidx[ii];
        }
        __syncthreads();
        if (tid < 128 && g0 + tid < cnt) {
            float b = rs[0][tid]; int bi = ri[0][tid];
#pragma unroll
            for (int j = 1; j < 16; ++j) {
                const float s = rs[j][tid]; const int i2 = ri[j][tid];
                if (s < b || (s == b && i2 < bi)) { b = s; bi = i2; }
            }
            const unsigned long long pk =
                ((unsigned long long)enc_f(b) << 32) | (unsigned)bi;
            atomicMin(&pbest[c * 8192 + g0 + tid], pk);
        }
    }
}

// ====== pass 3: gather winners for flagged tokens ======
__global__ void pass3(const float* __restrict__ cb, float* __restrict__ out,
                      const int* __restrict__ bcnt, const int* __restrict__ bwl,
                      const unsigned long long* __restrict__ pbest)
{
    const int c = blockIdx.y;
    const int cnt = bcnt[c];
    const float4* cg = (const float4*)cb;
    float4* og = (float4*)out;
    const int q = threadIdx.x & 15;
    for (int e = blockIdx.x * 16 + (threadIdx.x >> 4); e < cnt; e += 64 * 16) {
        const int tok = bwl[c * 8192 + e];
        const unsigned n = (unsigned)(pbest[c * 8192 + e] & 0xFFFFFFFFull);
        og[(size_t)tok * 256 + c * 16 + q] = cg[((size_t)c * NCODE + n) * 16 + q];
    }
}

extern "C" void kernel_launch(void* const* d_in, const int* in_sizes, int n_in,
                              void* d_out, int out_size, void* d_ws, size_t ws_size,
                              hipStream_t stream)
{
    const float* x  = (const float*)d_in[0];
    const float* cb = (const float*)d_in[1];
    float* out      = (float*)d_out;

    if (ws_size < (size_t)(2u << 20)) {
        dim3 grid(BS / 128, CCH);
        vq_fp32_fallback<<<grid, 256, 0, stream>>>(x, cb, out);
        return;
    }
    char* ws = (char*)d_ws;
    float* cbsq = (float*)ws;
    float* cmax = (float*)(ws + 131072);
    int*   bcnt = (int*)(ws + 131076);
    int*   bwl  = (int*)(ws + 131328);
    unsigned long long* pbest = (unsigned long long*)(ws + 655616);
    unsigned short* cbh = (unsigned short*)(ws + (2u << 20));
    unsigned short* cbl = (unsigned short*)(ws + (6u << 20));

    init_ws<<<1, 64, 0, stream>>>(cmax, bcnt);
    cbsq_kernel<<<CCH * NCODE / 256, 256, 0, stream>>>(cb, cbsq, cmax);
    if (ws_size >= (size_t)(10u << 20)) {
        presplit_cb<<<2048, 256, 0, stream>>>(cb, cbh, cbl);
        pass1<true><<<dim3(BS / 128, CCH), 256, 0, stream>>>(x, cb, cbh, cbl, cbsq, cmax, out, bcnt, bwl, pbest);
    } else {
        pass1<false><<<dim3(BS / 128, CCH), 256, 0, stream>>>(x, cb, nullptr, nullptr, cbsq, cmax, out, bcnt, bwl, pbest);
    }
    pass2_nt<<<dim3(16, CCH), 256, 0, stream>>>(x, cb, bcnt, bwl, pbest);
    pass3<<<dim3(64, CCH), 256, 0, stream>>>(cb, out, bcnt, bwl, pbest);
}